// Round 9
// baseline (85.672 us; speedup 1.0000x reference)
//
#include <hip/hip_runtime.h>

#define NT   24
#define CIN  9
#define NF   32
#define KM   16
#define HID  128
#define NCLS 10
#define SEQ_LEN (NT*CIN)   // 216
#define PADJ 12            // seq LDS row pitch; elem 9 holds ||x_j||^2
#define NSTRIP 4
#define SPB  4             // seqs per block (1 per wave)

typedef float vf2 __attribute__((ext_vector_type(2)));

// D[m-1,n-1] (forward DTW) == backtracked path-cost sum (telescoping).
// Cost via quadratic expansion, kf pre-scaled by -2, PACKED ACROSS THE TWO
// FILTERS each thread owns (v_pk_fma_f32): one wave = one sequence,
// lane = strip*16 + fpair; thread computes filters fp and fp+16 for rows
// [4s,4s+4). Two independent min-chains give 2-way ILP on the DP critical
// path; seq LDS reads are shared by 8 cells; column j+1 is prefetched
// before computing column j; ||x_j||^2 rides in the pad lane (q2.y).
// Boundary D per filter flows strip s -> s+1 via __shfl_up(.,16).
__global__ __launch_bounds__(256, 2) void dtwnet_fused(
    const float* __restrict__ x,
    const float* __restrict__ kern,
    const float* __restrict__ W1, const float* __restrict__ b1,
    const float* __restrict__ W2, const float* __restrict__ b2,
    const float* __restrict__ Wl, const float* __restrict__ bl,
    float* __restrict__ out)
{
  __shared__ float seq_lds[SPB*NT*PADJ];
  __shared__ float feat_lds[SPB*NF];
  __shared__ float h1_lds[SPB*HID];
  __shared__ float h2_lds[SPB*HID];
  __shared__ float logit_lds[SPB*NCLS];

  const int tid  = threadIdx.x;
  const int bid  = blockIdx.x;
  const int wave = tid >> 6;        // seq within block
  const int lane = tid & 63;
  const int s    = lane >> 4;       // strip 0..3 (rows 4s..4s+3)
  const int fp   = lane & 15;       // filter pair id: filters fp, fp+16

  // both filters' strips from global (18 KB, L2-hot), issued pre-barrier
  float kA[4*CIN], kB[4*CIN];
  {
    const float4* ka = (const float4*)(kern + fp*(KM*CIN) + s*(4*CIN));
    const float4* kb = (const float4*)(kern + (fp+16)*(KM*CIN) + s*(4*CIN));
    #pragma unroll
    for (int q = 0; q < 9; ++q) {
      float4 ta = ka[q], tb = kb[q];
      kA[4*q+0]=ta.x; kA[4*q+1]=ta.y; kA[4*q+2]=ta.z; kA[4*q+3]=ta.w;
      kB[4*q+0]=tb.x; kB[4*q+1]=tb.y; kB[4*q+2]=tb.z; kB[4*q+3]=tb.w;
    }
  }

  // stage 4 sequences (864 floats), padded to 12/timestep
  for (int d = tid; d < SPB*SEQ_LEN; d += 256) {
    int sq = d / SEQ_LEN;
    int r  = d - sq*SEQ_LEN;
    int jj = r / CIN, cc = r - jj*CIN;
    seq_lds[sq*NT*PADJ + jj*PADJ + cc] = x[bid*(SPB*SEQ_LEN) + d];
  }
  __syncthreads();

  // ||x_j||^2 into pad lane 9 (96 columns total)
  if (tid < SPB*NT) {
    int sq = tid / NT, j = tid - sq*NT;
    float* base = seq_lds + sq*NT*PADJ + j*PADJ;
    const float4* bp = (const float4*)base;
    float4 q0 = bp[0], q1 = bp[1];
    float v8 = base[8];
    base[9] = q0.x*q0.x + q0.y*q0.y + q0.z*q0.z + q0.w*q0.w
            + q1.x*q1.x + q1.y*q1.y + q1.z*q1.z + q1.w*q1.w
            + v8*v8;
  }

  // pack across filters, compute norms, pre-scale by -2
  vf2 kfp[4*CIN], arp[4];
  #pragma unroll
  for (int r = 0; r < 4; ++r) arp[r] = (vf2){0.f, 0.f};
  #pragma unroll
  for (int idx = 0; idx < 4*CIN; ++idx) {
    int r = idx / CIN;
    vf2 v = {kA[idx], kB[idx]};
    arp[r] = __builtin_elementwise_fma(v, v, arp[r]);
    kfp[idx] = v * (-2.f);
  }
  __syncthreads();

  const float4* spv = (const float4*)(seq_lds + wave*NT*PADJ);

  float rDA[4], rDB[4];
  float bUpA = 0.f, bDgA = 0.f, bUpB = 0.f, bDgB = 0.f;

  // preload column for t=0 (row 0; only strip 0 uses it)
  float4 q0 = spv[0], q1 = spv[1], q2 = spv[2];

  #pragma unroll 1
  for (int t = 0; t < NT + NSTRIP - 1; ++t) {   // 27 steps
    int j = t - s;
    // prefetch next column (clamped; always in-bounds)
    int jn = j + 1;
    jn = (jn < 0) ? 0 : ((jn > NT-1) ? NT-1 : jn);
    float4 m0 = spv[jn*3+0], m1 = spv[jn*3+1], m2 = spv[jn*3+2];

    float nbA = 0.f, nbB = 0.f;
    if (j >= 0 && j < NT) {
      float sv[CIN] = {q0.x,q0.y,q0.z,q0.w,q1.x,q1.y,q1.z,q1.w,q2.x};
      float bj = q2.y;                       // ||x_j||^2 from pad lane
      vf2 cst[4];
      #pragma unroll
      for (int r = 0; r < 4; ++r) {
        vf2 cc = arp[r] + bj;
        #pragma unroll
        for (int c = 0; c < CIN; ++c) {
          vf2 sc = {sv[c], sv[c]};
          cc = __builtin_elementwise_fma(kfp[r*CIN+c], sc, cc);
        }
        cst[r] = cc;
      }
      if (j == 0) {
        float aA = (s == 0) ? 0.f : bUpA;
        float aB = (s == 0) ? 0.f : bUpB;
        #pragma unroll
        for (int r = 0; r < 4; ++r) {
          aA += cst[r].x; rDA[r] = aA;
          aB += cst[r].y; rDB[r] = aB;
        }
      } else {
        // filter A chain
        {
          float l0 = rDA[0];
          float D0 = (s == 0) ? (cst[0].x + l0)
                              : (cst[0].x + fminf(bDgA, fminf(bUpA, l0)));
          float dg = l0, up = D0; rDA[0] = D0;
          #pragma unroll
          for (int r = 1; r < 4; ++r) {
            float l = rDA[r];
            float D = cst[r].x + fminf(dg, fminf(up, l));
            dg = l; rDA[r] = D; up = D;
          }
        }
        // filter B chain (independent -> ILP)
        {
          float l0 = rDB[0];
          float D0 = (s == 0) ? (cst[0].y + l0)
                              : (cst[0].y + fminf(bDgB, fminf(bUpB, l0)));
          float dg = l0, up = D0; rDB[0] = D0;
          #pragma unroll
          for (int r = 1; r < 4; ++r) {
            float l = rDB[r];
            float D = cst[r].y + fminf(dg, fminf(up, l));
            dg = l; rDB[r] = D; up = D;
          }
        }
      }
      nbA = rDA[3]; nbB = rDB[3];
    }
    float rA = __shfl_up(nbA, 16u);
    float rB = __shfl_up(nbB, 16u);
    bDgA = bUpA; bUpA = rA;
    bDgB = bUpB; bUpB = rB;
    q0 = m0; q1 = m1; q2 = m2;
  }

  if (s == NSTRIP-1) {
    feat_lds[wave*NF + fp]      = rDA[3];
    feat_lds[wave*NF + fp + 16] = rDB[3];
  }
  __syncthreads();

  // --- MLP, weight loads shared across the 4 sequences (threads 0..127) ---
  if (tid < HID) {
    float a0 = b1[tid], a1 = a0, a2 = a0, a3 = a0;
    #pragma unroll
    for (int k = 0; k < NF; ++k) {
      float w = W1[k*HID + tid];
      a0 = fmaf(feat_lds[0*NF + k], w, a0);
      a1 = fmaf(feat_lds[1*NF + k], w, a1);
      a2 = fmaf(feat_lds[2*NF + k], w, a2);
      a3 = fmaf(feat_lds[3*NF + k], w, a3);
    }
    h1_lds[0*HID + tid] = fmaxf(a0, 0.f);
    h1_lds[1*HID + tid] = fmaxf(a1, 0.f);
    h1_lds[2*HID + tid] = fmaxf(a2, 0.f);
    h1_lds[3*HID + tid] = fmaxf(a3, 0.f);
  }
  __syncthreads();
  if (tid < HID) {
    const float4* h0 = (const float4*)(h1_lds + 0*HID);
    const float4* h1v = (const float4*)(h1_lds + 1*HID);
    const float4* h2v = (const float4*)(h1_lds + 2*HID);
    const float4* h3v = (const float4*)(h1_lds + 3*HID);
    float p0 = b2[tid], p1 = 0.f, p2 = 0.f, p3 = 0.f;
    float q0_ = b2[tid], q1_ = 0.f, q2_ = 0.f, q3_ = 0.f;
    float r0 = b2[tid], r1 = 0.f, r2 = 0.f, r3 = 0.f;
    float s0 = b2[tid], s1 = 0.f, s2 = 0.f, s3 = 0.f;
    #pragma unroll
    for (int k = 0; k < HID/4; ++k) {
      float w0 = W2[(4*k+0)*HID + tid];
      float w1 = W2[(4*k+1)*HID + tid];
      float w2 = W2[(4*k+2)*HID + tid];
      float w3 = W2[(4*k+3)*HID + tid];
      float4 ha = h0[k], hb = h1v[k], hc = h2v[k], hd = h3v[k];
      p0 = fmaf(ha.x, w0, p0); p1 = fmaf(ha.y, w1, p1);
      p2 = fmaf(ha.z, w2, p2); p3 = fmaf(ha.w, w3, p3);
      q0_ = fmaf(hb.x, w0, q0_); q1_ = fmaf(hb.y, w1, q1_);
      q2_ = fmaf(hb.z, w2, q2_); q3_ = fmaf(hb.w, w3, q3_);
      r0 = fmaf(hc.x, w0, r0); r1 = fmaf(hc.y, w1, r1);
      r2 = fmaf(hc.z, w2, r2); r3 = fmaf(hc.w, w3, r3);
      s0 = fmaf(hd.x, w0, s0); s1 = fmaf(hd.y, w1, s1);
      s2 = fmaf(hd.z, w2, s2); s3 = fmaf(hd.w, w3, s3);
    }
    h2_lds[0*HID + tid] = fmaxf((p0 + p1) + (p2 + p3), 0.f);
    h2_lds[1*HID + tid] = fmaxf((q0_ + q1_) + (q2_ + q3_), 0.f);
    h2_lds[2*HID + tid] = fmaxf((r0 + r1) + (r2 + r3), 0.f);
    h2_lds[3*HID + tid] = fmaxf((s0 + s1) + (s2 + s3), 0.f);
  }
  __syncthreads();
  if (tid < SPB*NCLS) {              // 40 threads: one (seq,class) each
    int sq = tid / NCLS, j = tid - sq*NCLS;
    const float4* hh = (const float4*)(h2_lds + sq*HID);
    float a0 = bl[j], a1 = 0.f, a2 = 0.f, a3 = 0.f;
    #pragma unroll
    for (int k = 0; k < HID/4; ++k) {
      float4 h4 = hh[k];
      a0 = fmaf(h4.x, Wl[(4*k+0)*NCLS + j], a0);
      a1 = fmaf(h4.y, Wl[(4*k+1)*NCLS + j], a1);
      a2 = fmaf(h4.z, Wl[(4*k+2)*NCLS + j], a2);
      a3 = fmaf(h4.w, Wl[(4*k+3)*NCLS + j], a3);
    }
    logit_lds[tid] = (a0 + a1) + (a2 + a3);
  }
  __syncthreads();
  if (tid < SPB) {
    const float* lg = &logit_lds[tid*NCLS];
    float mx = lg[0];
    #pragma unroll
    for (int j = 1; j < NCLS; ++j) mx = fmaxf(mx, lg[j]);
    float e[NCLS]; float sum = 0.f;
    #pragma unroll
    for (int j = 0; j < NCLS; ++j) { e[j] = __expf(lg[j] - mx); sum += e[j]; }
    float inv = 1.f / sum;
    float* op = out + (bid*SPB + tid)*NCLS;
    #pragma unroll
    for (int j = 0; j < NCLS; ++j) op[j] = e[j] * inv;
  }
}

extern "C" void kernel_launch(void* const* d_in, const int* in_sizes, int n_in,
                              void* d_out, int out_size, void* d_ws, size_t ws_size,
                              hipStream_t stream) {
  const float* x    = (const float*)d_in[0];
  const float* kern = (const float*)d_in[1];
  const float* W1   = (const float*)d_in[2];
  const float* b1   = (const float*)d_in[3];
  const float* W2   = (const float*)d_in[4];
  const float* b2   = (const float*)d_in[5];
  const float* Wl   = (const float*)d_in[6];
  const float* bl   = (const float*)d_in[7];
  float* out = (float*)d_out;

  // 2048 sequences, 4 per block (1 per wave)
  dtwnet_fused<<<512, 256, 0, stream>>>(x, kern, W1, b1, W2, b2, Wl, bl, out);
}

// Round 10
// 84.442 us; speedup vs baseline: 1.0146x; 1.0146x over previous
//
#include <hip/hip_runtime.h>

#define NT   24
#define CIN  9
#define NF   32
#define KM   16
#define HID  128
#define NCLS 10
#define SEQ_LEN (NT*CIN)   // 216
#define PADJ 12            // seq LDS row pitch (floats), 16B-aligned columns
#define NSTRIP 4           // 4 strips of 4 rows; pipelined via shfl

// FINAL (reverted to best-measured R6 variant, 84.0 µs):
// D[m-1,n-1] (forward DTW) == backtracked path-cost sum (telescoping; only fp
// summation order differs). Cost uses the quadratic expansion:
//   ||k-x||^2 = ||k||^2 + ||x||^2 - 2 k.x
// with kf pre-scaled by -2 and the accumulator seeded with a[r]+b[j]:
// per cell = 1 add + 9 fma. D is min-plus in the costs, so near-tie path
// flips do not perturb D.
//
// Thread layout: block = 128 threads = 2 waves, 1 sequence per block.
// lane = strip*16 + f_lo ; filter f = wave*16 + f_lo.
// Strip s computes rows [4s,4s+4), skewed: step t works column j = t-s.
// Boundary D flows strip s -> s+1 via __shfl_up(.,16).
__global__ __launch_bounds__(128, 4) void dtwnet_fused(
    const float* __restrict__ x,
    const float* __restrict__ kern,
    const float* __restrict__ W1, const float* __restrict__ b1,
    const float* __restrict__ W2, const float* __restrict__ b2,
    const float* __restrict__ Wl, const float* __restrict__ bl,
    float* __restrict__ out)
{
  __shared__ float seq_lds[NT*PADJ];
  __shared__ float bcol[NT];          // ||x_j||^2 per column
  __shared__ float feat_lds[NF];
  __shared__ float h1_lds[HID];
  __shared__ float h2_lds[HID];
  __shared__ float logit_lds[NCLS];

  const int tid  = threadIdx.x;
  const int bid  = blockIdx.x;
  const int wave = tid >> 6;
  const int lane = tid & 63;
  const int s    = lane >> 4;       // strip 0..3
  const int f_lo = lane & 15;
  const int f    = wave*16 + f_lo;  // filter 0..31

  // filter strip (4 rows x 9 ch) from global (L2-hot), issued pre-barrier
  float kf[4*CIN];
  {
    const float4* kp = (const float4*)(kern + f*(KM*CIN) + s*(4*CIN));
    float4 t0 = kp[0], t1 = kp[1], t2 = kp[2], t3 = kp[3], t4 = kp[4],
           t5 = kp[5], t6 = kp[6], t7 = kp[7], t8 = kp[8];
    kf[0]=t0.x; kf[1]=t0.y; kf[2]=t0.z; kf[3]=t0.w;
    kf[4]=t1.x; kf[5]=t1.y; kf[6]=t1.z; kf[7]=t1.w;
    kf[8]=t2.x; kf[9]=t2.y; kf[10]=t2.z; kf[11]=t2.w;
    kf[12]=t3.x; kf[13]=t3.y; kf[14]=t3.z; kf[15]=t3.w;
    kf[16]=t4.x; kf[17]=t4.y; kf[18]=t4.z; kf[19]=t4.w;
    kf[20]=t5.x; kf[21]=t5.y; kf[22]=t5.z; kf[23]=t5.w;
    kf[24]=t6.x; kf[25]=t6.y; kf[26]=t6.z; kf[27]=t6.w;
    kf[28]=t7.x; kf[29]=t7.y; kf[30]=t7.z; kf[31]=t7.w;
    kf[32]=t8.x; kf[33]=t8.y; kf[34]=t8.z; kf[35]=t8.w;
  }

  // stage this block's sequence (216 floats), padded to 12/timestep
  for (int d = tid; d < SEQ_LEN; d += 128) {
    int jj = d / CIN, cc = d - jj*CIN;
    seq_lds[jj*PADJ + cc] = x[bid*SEQ_LEN + d];
  }
  __syncthreads();

  // column norms ||x_j||^2 (24 values, one thread each)
  if (tid < NT) {
    const float4* sp = (const float4*)(seq_lds + tid*PADJ);
    float4 q0 = sp[0], q1 = sp[1], q2 = sp[2];
    bcol[tid] = q0.x*q0.x + q0.y*q0.y + q0.z*q0.z + q0.w*q0.w
              + q1.x*q1.x + q1.y*q1.y + q1.z*q1.z + q1.w*q1.w
              + q2.x*q2.x;
  }

  // a[r] = ||k_r||^2, then pre-scale kf by -2
  float arow[4];
  #pragma unroll
  for (int r = 0; r < 4; ++r) {
    float a = 0.f;
    #pragma unroll
    for (int c = 0; c < CIN; ++c) a = fmaf(kf[r*CIN+c], kf[r*CIN+c], a);
    arow[r] = a;
  }
  #pragma unroll
  for (int q = 0; q < 4*CIN; ++q) kf[q] *= -2.f;
  __syncthreads();

  float rowD[4];
  float bndUp = 0.f, bndDg = 0.f;

  #pragma unroll 1
  for (int t = 0; t < NT + NSTRIP - 1; ++t) {
    int j = t - s;                        // this strip's column
    bool active = (j >= 0) && (j < NT);
    float nb = 0.f;
    if (active) {
      const float4* sp = (const float4*)(seq_lds + j*PADJ);
      float4 q0 = sp[0], q1 = sp[1], q2 = sp[2];
      float bj = bcol[j];
      float sv[CIN] = {q0.x,q0.y,q0.z,q0.w,q1.x,q1.y,q1.z,q1.w,q2.x};
      float cost[4];
      #pragma unroll
      for (int r = 0; r < 4; ++r) {
        float cc = arow[r] + bj;
        #pragma unroll
        for (int c = 0; c < CIN; ++c) cc = fmaf(kf[r*CIN+c], sv[c], cc);
        cost[r] = cc;
      }
      if (j == 0) {
        // column 0: up-only chain (row 0 starts at 0)
        float acc = (s == 0) ? 0.f : bndUp;
        #pragma unroll
        for (int r = 0; r < 4; ++r) { acc += cost[r]; rowD[r] = acc; }
      } else {
        float up, diag;
        float left = rowD[0];
        float D0;
        if (s == 0) {
          D0 = cost[0] + left;                       // global row 0: left-only
        } else {
          D0 = cost[0] + fminf(bndDg, fminf(bndUp, left));
        }
        diag = left;
        rowD[0] = D0; up = D0;
        #pragma unroll
        for (int r = 1; r < 4; ++r) {
          float lD = rowD[r];
          float D2 = cost[r] + fminf(diag, fminf(up, lD));
          diag = lD;
          rowD[r] = D2; up = D2;
        }
      }
      nb = rowD[3];
    }
    // wave-wide boundary hand-off to the next strip
    float rD = __shfl_up(nb, 16u);
    bndDg = bndUp;
    bndUp = rD;
  }

  if (s == 3) feat_lds[f] = rowD[3];
  __syncthreads();

  // --- MLP: 32 -> 128 relu -> 128 relu -> 10 softmax (1 seq / block) ---
  {
    float acc = b1[tid];
    #pragma unroll
    for (int k = 0; k < NF; ++k) acc = fmaf(feat_lds[k], W1[k*HID + tid], acc);
    h1_lds[tid] = fmaxf(acc, 0.f);
  }
  __syncthreads();
  {
    const float4* hh = (const float4*)h1_lds;
    float a0 = b2[tid], a1 = 0.f, a2 = 0.f, a3 = 0.f;
    #pragma unroll
    for (int k = 0; k < HID/4; ++k) {
      float4 h4 = hh[k];
      a0 = fmaf(h4.x, W2[(4*k+0)*HID + tid], a0);
      a1 = fmaf(h4.y, W2[(4*k+1)*HID + tid], a1);
      a2 = fmaf(h4.z, W2[(4*k+2)*HID + tid], a2);
      a3 = fmaf(h4.w, W2[(4*k+3)*HID + tid], a3);
    }
    h2_lds[tid] = fmaxf((a0 + a1) + (a2 + a3), 0.f);
  }
  __syncthreads();
  if (tid < NCLS) {
    const float4* hh = (const float4*)h2_lds;
    float a0 = bl[tid], a1 = 0.f, a2 = 0.f, a3 = 0.f;
    #pragma unroll
    for (int k = 0; k < HID/4; ++k) {
      float4 h4 = hh[k];
      a0 = fmaf(h4.x, Wl[(4*k+0)*NCLS + tid], a0);
      a1 = fmaf(h4.y, Wl[(4*k+1)*NCLS + tid], a1);
      a2 = fmaf(h4.z, Wl[(4*k+2)*NCLS + tid], a2);
      a3 = fmaf(h4.w, Wl[(4*k+3)*NCLS + tid], a3);
    }
    logit_lds[tid] = (a0 + a1) + (a2 + a3);
  }
  __syncthreads();
  if (tid == 0) {
    float mx = logit_lds[0];
    #pragma unroll
    for (int j = 1; j < NCLS; ++j) mx = fmaxf(mx, logit_lds[j]);
    float e[NCLS]; float sum = 0.f;
    #pragma unroll
    for (int j = 0; j < NCLS; ++j) { e[j] = __expf(logit_lds[j] - mx); sum += e[j]; }
    float inv = 1.f / sum;
    float* op = out + bid*NCLS;
    #pragma unroll
    for (int j = 0; j < NCLS; ++j) op[j] = e[j] * inv;
  }
}

extern "C" void kernel_launch(void* const* d_in, const int* in_sizes, int n_in,
                              void* d_out, int out_size, void* d_ws, size_t ws_size,
                              hipStream_t stream) {
  const float* x    = (const float*)d_in[0];
  const float* kern = (const float*)d_in[1];
  const float* W1   = (const float*)d_in[2];
  const float* b1   = (const float*)d_in[3];
  const float* W2   = (const float*)d_in[4];
  const float* b2   = (const float*)d_in[5];
  const float* Wl   = (const float*)d_in[6];
  const float* bl   = (const float*)d_in[7];
  float* out = (float*)d_out;

  dtwnet_fused<<<2048, 128, 0, stream>>>(x, kern, W1, b1, W2, b2, Wl, bl, out);
}